// Round 2
// baseline (1180.881 us; speedup 1.0000x reference)
//
#include <hip/hip_runtime.h>
#include <math.h>

#define NN 50000
#define NE 800000
#define TN 16

__device__ __forceinline__ float relu(float v) { return fmaxf(v, 0.0f); }

// ---- degree count over dst ----
__global__ __launch_bounds__(256) void k_deg(const int* __restrict__ ei,
                                             int* __restrict__ deg) {
  int e = blockIdx.x * 256 + threadIdx.x;
  if (e < NE) atomicAdd(&deg[ei[NE + e]], 1);
}

// ---- d^-1/2 ----
__global__ __launch_bounds__(256) void k_dinv(const int* __restrict__ deg,
                                              float* __restrict__ dinv) {
  int i = blockIdx.x * 256 + threadIdx.x;
  if (i < NN) {
    int d = deg[i];
    dinv[i] = d > 0 ? 1.0f / sqrtf((float)d) : 0.0f;
  }
}

// ---- exclusive scan of deg -> rowptr (single block, wave-scan + carry) ----
__global__ __launch_bounds__(256) void k_scan(const int* __restrict__ deg,
                                              int* __restrict__ rowptr) {
  __shared__ int swave[4];
  __shared__ int scarry;
  const int tid = threadIdx.x;
  const int lane = tid & 63;
  const int wid = tid >> 6;
  if (tid == 0) scarry = 0;
  __syncthreads();
  for (int base = 0; base < NN; base += 256) {
    int i = base + tid;
    int v = (i < NN) ? deg[i] : 0;
    int sum = v;
#pragma unroll
    for (int off = 1; off < 64; off <<= 1) {
      int t = __shfl_up(sum, off);
      if (lane >= off) sum += t;
    }
    if (lane == 63) swave[wid] = sum;
    __syncthreads();
    int wbase = 0;
    for (int w = 0; w < 4; ++w)
      if (w < wid) wbase += swave[w];
    int carry = scarry;
    if (i < NN) rowptr[i] = carry + wbase + sum - v;
    __syncthreads();
    if (tid == 255) scarry = carry + swave[0] + swave[1] + swave[2] + swave[3];
    __syncthreads();
  }
  if (tid == 0) rowptr[NN] = scarry;
}

// ---- CSR fill + edge weights ----
__global__ __launch_bounds__(256) void k_fill(const int* __restrict__ ei,
                                              const float* __restrict__ dinv,
                                              const int* __restrict__ rowptr,
                                              int* __restrict__ fill,
                                              int* __restrict__ col,
                                              float* __restrict__ wgt) {
  int e = blockIdx.x * 256 + threadIdx.x;
  if (e < NE) {
    int s = ei[e];
    int d = ei[NE + e];
    float w = dinv[s] * dinv[d] * 0.5f;
    int pos = rowptr[d] + atomicAdd(&fill[d], 1);
    col[pos] = s;
    wgt[pos] = w;
  }
}

// ---- one propagation hop: out[i] = 0.5*in[i] + sum_e w_e * in[col_e] ----
__global__ __launch_bounds__(256) void k_hop(const float* __restrict__ in,
                                             float* __restrict__ out,
                                             const int* __restrict__ rowptr,
                                             const int* __restrict__ col,
                                             const float* __restrict__ wgt) {
  int g = (blockIdx.x * 256 + threadIdx.x) >> 5;  // node, 32 threads/node
  int lane = threadIdx.x & 31;
  if (g >= NN) return;
  const float4* in4 = (const float4*)in;
  float4 acc = in4[g * 32 + lane];
  acc.x *= 0.5f; acc.y *= 0.5f; acc.z *= 0.5f; acc.w *= 0.5f;
  int e1 = rowptr[g + 1];
  for (int e = rowptr[g]; e < e1; ++e) {
    int c = col[e];
    float w = wgt[e];
    float4 v = in4[c * 32 + lane];
    acc.x += w * v.x; acc.y += w * v.y; acc.z += w * v.z; acc.w += w * v.w;
  }
  ((float4*)out)[g * 32 + lane] = acc;
}

// ---- fused: 7-channel GEMM + channel attention + MLP ----
__global__ __launch_bounds__(256) void k_fused(
    const float* __restrict__ a0, const float* __restrict__ a1,
    const float* __restrict__ a2, const float* __restrict__ a4,
    const float* __restrict__ W_low, const float* __restrict__ b_low,
    const float* __restrict__ W_band, const float* __restrict__ b_band,
    const float* __restrict__ apre_l, const float* __restrict__ ach_l,
    const float* __restrict__ apre_b, const float* __restrict__ ach_b,
    const float* __restrict__ W_mlp, const float* __restrict__ b_mlp,
    float* __restrict__ out) {
  __shared__ float sW[128 * 128];    // 64 KiB
  __shared__ float sH[7][TN * 128];  // 56 KiB
  __shared__ float sF[TN * 128];     // 8 KiB

  const int tid = threadIdx.x;
  const int node0 = blockIdx.x * TN;
  const int c0 = (tid & 31) * 4;   // GEMM: output col group
  const int r0 = (tid >> 5) * 2;   // GEMM: row pair

  for (int c = 0; c < 7; ++c) {
    const float* Wsrc = (c < 4) ? (W_low + c * 16384) : (W_band + (c - 4) * 16384);
    for (int i = tid; i < 4096; i += 256)
      ((float4*)sW)[i] = ((const float4*)Wsrc)[i];
    for (int i = tid; i < TN * 32; i += 256) {
      int idx = node0 * 32 + i;
      float4 f;
      if (c == 0)      f = ((const float4*)a0)[idx];
      else if (c == 1) f = ((const float4*)a1)[idx];
      else if (c == 2) f = ((const float4*)a2)[idx];
      else if (c == 3) f = ((const float4*)a4)[idx];
      else {
        const float4 *pa, *pb;
        if (c == 4)      { pa = (const float4*)a0; pb = (const float4*)a1; }
        else if (c == 5) { pa = (const float4*)a1; pb = (const float4*)a2; }
        else             { pa = (const float4*)a2; pb = (const float4*)a4; }
        float4 u = pa[idx], v = pb[idx];
        f = make_float4(u.x - v.x, u.y - v.y, u.z - v.z, u.w - v.w);
      }
      ((float4*)sF)[i] = f;
    }
    __syncthreads();
    float acc00 = 0, acc01 = 0, acc02 = 0, acc03 = 0;
    float acc10 = 0, acc11 = 0, acc12 = 0, acc13 = 0;
    for (int k = 0; k < 128; ++k) {
      float f0 = sF[r0 * 128 + k];
      float f1 = sF[(r0 + 1) * 128 + k];
      float4 w = *(const float4*)&sW[k * 128 + c0];
      acc00 += f0 * w.x; acc01 += f0 * w.y; acc02 += f0 * w.z; acc03 += f0 * w.w;
      acc10 += f1 * w.x; acc11 += f1 * w.y; acc12 += f1 * w.z; acc13 += f1 * w.w;
    }
    const float* bias = (c < 4) ? (b_low + c * 128) : (b_band + (c - 4) * 128);
    float4 b4 = *(const float4*)&bias[c0];
    *(float4*)&sH[c][r0 * 128 + c0] =
        make_float4(acc00 + b4.x, acc01 + b4.y, acc02 + b4.z, acc03 + b4.w);
    *(float4*)&sH[c][(r0 + 1) * 128 + c0] =
        make_float4(acc10 + b4.x, acc11 + b4.y, acc12 + b4.z, acc13 + b4.w);
    __syncthreads();
  }

  // ---- attention: 16 threads per node, 8 cols each ----
  const int r = tid >> 4;
  const int o0 = (tid & 15) * 8;
  float hv[7][8];
#pragma unroll
  for (int c = 0; c < 7; ++c) {
    float4 t0 = *(const float4*)&sH[c][r * 128 + o0];
    float4 t1 = *(const float4*)&sH[c][r * 128 + o0 + 4];
    hv[c][0] = t0.x; hv[c][1] = t0.y; hv[c][2] = t0.z; hv[c][3] = t0.w;
    hv[c][4] = t1.x; hv[c][5] = t1.y; hv[c][6] = t1.z; hv[c][7] = t1.w;
  }
  float dpl = 0.0f, dpb = 0.0f;
  float sc0 = 0, sc1 = 0, sc2 = 0, sc3 = 0, sc4 = 0, sc5 = 0, sc6 = 0;
#pragma unroll
  for (int j = 0; j < 8; ++j) {
    float r0l = relu(hv[0][j]), r1l = relu(hv[1][j]);
    float r2l = relu(hv[2][j]), r3l = relu(hv[3][j]);
    float r4b = relu(hv[4][j]), r5b = relu(hv[5][j]), r6b = relu(hv[6][j]);
    float apl = apre_l[o0 + j], acl = ach_l[o0 + j];
    float apb = apre_b[o0 + j], acb = ach_b[o0 + j];
    dpl += 0.25f * (r0l + r1l + r2l + r3l) * apl;
    dpb += (1.0f / 3.0f) * (r4b + r5b + r6b) * apb;
    sc0 += r0l * acl; sc1 += r1l * acl; sc2 += r2l * acl; sc3 += r3l * acl;
    sc4 += r4b * acb; sc5 += r5b * acb; sc6 += r6b * acb;
  }
#pragma unroll
  for (int m = 1; m <= 8; m <<= 1) {
    dpl += __shfl_xor(dpl, m); dpb += __shfl_xor(dpb, m);
    sc0 += __shfl_xor(sc0, m); sc1 += __shfl_xor(sc1, m);
    sc2 += __shfl_xor(sc2, m); sc3 += __shfl_xor(sc3, m);
    sc4 += __shfl_xor(sc4, m); sc5 += __shfl_xor(sc5, m);
    sc6 += __shfl_xor(sc6, m);
  }
  float lg0 = relu(dpl + sc0), lg1 = relu(dpl + sc1);
  float lg2 = relu(dpl + sc2), lg3 = relu(dpl + sc3);
  float lg4 = relu(dpb + sc4), lg5 = relu(dpb + sc5), lg6 = relu(dpb + sc6);
  float ml = fmaxf(fmaxf(lg0, lg1), fmaxf(lg2, lg3));
  float e0 = expf(lg0 - ml), e1 = expf(lg1 - ml);
  float e2 = expf(lg2 - ml), e3 = expf(lg3 - ml);
  float invl = 1.0f / (e0 + e1 + e2 + e3);
  float al0 = e0 * invl, al1 = e1 * invl, al2 = e2 * invl, al3 = e3 * invl;
  float mb = fmaxf(fmaxf(lg4, lg5), lg6);
  float f4 = expf(lg4 - mb), f5 = expf(lg5 - mb), f6 = expf(lg6 - mb);
  float invb = 1.0f / (f4 + f5 + f6);
  float ab4 = f4 * invb, ab5 = f5 * invb, ab6 = f6 * invb;

  float vlow[8], vband[8];
#pragma unroll
  for (int j = 0; j < 8; ++j) {
    vlow[j] = al0 * hv[0][j] + al1 * hv[1][j] + al2 * hv[2][j] + al3 * hv[3][j];
    vband[j] = ab4 * hv[4][j] + ab5 * hv[5][j] + ab6 * hv[6][j];
  }
  __syncthreads();  // everyone done reading sH
  float* vbuf = &sH[0][0];  // reuse: [TN][256]
#pragma unroll
  for (int j = 0; j < 8; j += 4) {
    *(float4*)&vbuf[r * 256 + o0 + j] =
        make_float4(vlow[j], vlow[j + 1], vlow[j + 2], vlow[j + 3]);
    *(float4*)&vbuf[r * 256 + 128 + o0 + j] =
        make_float4(vband[j], vband[j + 1], vband[j + 2], vband[j + 3]);
  }
  __syncthreads();

  // ---- MLP: [TN,256] @ [256,128] + b ----
  float m00 = 0, m01 = 0, m02 = 0, m03 = 0;
  float m10 = 0, m11 = 0, m12 = 0, m13 = 0;
  for (int h = 0; h < 2; ++h) {
    for (int i = tid; i < 4096; i += 256)
      ((float4*)sW)[i] = ((const float4*)(W_mlp + h * 16384))[i];
    __syncthreads();
    for (int k = 0; k < 128; ++k) {
      float f0 = vbuf[r0 * 256 + h * 128 + k];
      float f1 = vbuf[(r0 + 1) * 256 + h * 128 + k];
      float4 w = *(const float4*)&sW[k * 128 + c0];
      m00 += f0 * w.x; m01 += f0 * w.y; m02 += f0 * w.z; m03 += f0 * w.w;
      m10 += f1 * w.x; m11 += f1 * w.y; m12 += f1 * w.z; m13 += f1 * w.w;
    }
    __syncthreads();
  }
  float4 bm = *(const float4*)&b_mlp[c0];
  *(float4*)&out[(node0 + r0) * 128 + c0] =
      make_float4(m00 + bm.x, m01 + bm.y, m02 + bm.z, m03 + bm.w);
  *(float4*)&out[(node0 + r0 + 1) * 128 + c0] =
      make_float4(m10 + bm.x, m11 + bm.y, m12 + bm.z, m13 + bm.w);
}

extern "C" void kernel_launch(void* const* d_in, const int* in_sizes, int n_in,
                              void* d_out, int out_size, void* d_ws, size_t ws_size,
                              hipStream_t stream) {
  const float* x      = (const float*)d_in[0];
  const int* ei       = (const int*)d_in[1];   // harness passes integers as int32
  const float* W_low  = (const float*)d_in[2];
  const float* b_low  = (const float*)d_in[3];
  const float* W_band = (const float*)d_in[4];
  const float* b_band = (const float*)d_in[5];
  const float* apre_l = (const float*)d_in[6];
  const float* ach_l  = (const float*)d_in[7];
  const float* apre_b = (const float*)d_in[8];
  const float* ach_b  = (const float*)d_in[9];
  const float* W_mlp  = (const float*)d_in[10];
  const float* b_mlp  = (const float*)d_in[11];
  float* out = (float*)d_out;

  char* ws = (char*)d_ws;
  size_t off = 0;
  auto take = [&](size_t bytes) -> void* {
    void* p = ws + off;
    off = (off + bytes + 255) & ~(size_t)255;
    return p;
  };
  int*   deg    = (int*)take((size_t)NN * 4);
  int*   fill   = (int*)take((size_t)NN * 4);
  size_t zero_bytes = off;  // deg + fill region
  float* dinv   = (float*)take((size_t)NN * 4);
  int*   rowptr = (int*)take((size_t)(NN + 1) * 4);
  int*   col    = (int*)take((size_t)NE * 4);
  float* wgt    = (float*)take((size_t)NE * 4);
  float* a1v    = (float*)take((size_t)NN * 128 * 4);
  float* a2v    = (float*)take((size_t)NN * 128 * 4);
  float* a3v    = (float*)take((size_t)NN * 128 * 4);
  float* a4v    = (float*)take((size_t)NN * 128 * 4);
  (void)ws_size; (void)in_sizes; (void)n_in; (void)out_size;

  hipMemsetAsync(d_ws, 0, zero_bytes, stream);
  k_deg<<<(NE + 255) / 256, 256, 0, stream>>>(ei, deg);
  k_dinv<<<(NN + 255) / 256, 256, 0, stream>>>(deg, dinv);
  k_scan<<<1, 256, 0, stream>>>(deg, rowptr);
  k_fill<<<(NE + 255) / 256, 256, 0, stream>>>(ei, dinv, rowptr, fill, col, wgt);
  k_hop<<<(NN + 7) / 8, 256, 0, stream>>>(x,   a1v, rowptr, col, wgt);
  k_hop<<<(NN + 7) / 8, 256, 0, stream>>>(a1v, a2v, rowptr, col, wgt);
  k_hop<<<(NN + 7) / 8, 256, 0, stream>>>(a2v, a3v, rowptr, col, wgt);
  k_hop<<<(NN + 7) / 8, 256, 0, stream>>>(a3v, a4v, rowptr, col, wgt);
  k_fused<<<NN / TN, 256, 0, stream>>>(x, a1v, a2v, a4v, W_low, b_low, W_band, b_band,
                                       apre_l, ach_l, apre_b, ach_b, W_mlp, b_mlp, out);
}

// Round 3
// 626.811 us; speedup vs baseline: 1.8840x; 1.8840x over previous
//
#include <hip/hip_runtime.h>
#include <math.h>

#define NN 50000
#define NE 800000
#define TM 16

typedef _Float16 half4v __attribute__((ext_vector_type(4)));
typedef _Float16 half8v __attribute__((ext_vector_type(8)));
typedef float f32x4 __attribute__((ext_vector_type(4)));

__device__ __forceinline__ float relu(float v) { return fmaxf(v, 0.0f); }

// ---- degree count over dst ----
__global__ __launch_bounds__(256) void k_deg(const int* __restrict__ ei,
                                             int* __restrict__ deg) {
  int e = blockIdx.x * 256 + threadIdx.x;
  if (e < NE) atomicAdd(&deg[ei[NE + e]], 1);
}

// ---- d^-1/2 ----
__global__ __launch_bounds__(256) void k_dinv(const int* __restrict__ deg,
                                              float* __restrict__ dinv) {
  int i = blockIdx.x * 256 + threadIdx.x;
  if (i < NN) {
    int d = deg[i];
    dinv[i] = d > 0 ? 1.0f / sqrtf((float)d) : 0.0f;
  }
}

// ---- exclusive scan of deg -> rowptr (single 1024-thread block) ----
__global__ __launch_bounds__(1024) void k_scan(const int* __restrict__ deg,
                                               int* __restrict__ rowptr) {
  __shared__ int swave[16];
  __shared__ int scarry;
  const int tid = threadIdx.x;
  const int lane = tid & 63;
  const int wid = tid >> 6;
  if (tid == 0) scarry = 0;
  __syncthreads();
  for (int base = 0; base < NN; base += 1024) {
    int i = base + tid;
    int v = (i < NN) ? deg[i] : 0;
    int sum = v;
#pragma unroll
    for (int off = 1; off < 64; off <<= 1) {
      int t = __shfl_up(sum, off);
      if (lane >= off) sum += t;
    }
    if (lane == 63) swave[wid] = sum;
    __syncthreads();
    int wbase = 0;
    for (int w = 0; w < wid; ++w) wbase += swave[w];
    int carry = scarry;
    if (i < NN) rowptr[i] = carry + wbase + sum - v;
    __syncthreads();
    if (tid == 1023) scarry = carry + wbase + sum;
    __syncthreads();
  }
  if (tid == 0) rowptr[NN] = scarry;
}

// ---- CSR fill + edge weights ----
__global__ __launch_bounds__(256) void k_fill(const int* __restrict__ ei,
                                              const float* __restrict__ dinv,
                                              const int* __restrict__ rowptr,
                                              int* __restrict__ fill,
                                              int* __restrict__ col,
                                              float* __restrict__ wgt) {
  int e = blockIdx.x * 256 + threadIdx.x;
  if (e < NE) {
    int s = ei[e];
    int d = ei[NE + e];
    float w = dinv[s] * dinv[d] * 0.5f;
    int pos = rowptr[d] + atomicAdd(&fill[d], 1);
    col[pos] = s;
    wgt[pos] = w;
  }
}

// ---- one hop: out[i] = 0.5*in[i] + sum_e w_e * in[col_e]; 4-deep pipelined ----
__global__ __launch_bounds__(256) void k_hop(const float* __restrict__ in,
                                             float* __restrict__ out,
                                             const int* __restrict__ rowptr,
                                             const int* __restrict__ col,
                                             const float* __restrict__ wgt) {
  int g = (blockIdx.x * 256 + threadIdx.x) >> 5;  // node, 32 threads/node
  int lane = threadIdx.x & 31;
  if (g >= NN) return;
  const float4* in4 = (const float4*)in;
  float4 a = in4[g * 32 + lane];
  float4 acc = make_float4(0.5f * a.x, 0.5f * a.y, 0.5f * a.z, 0.5f * a.w);
  int e = rowptr[g], e1 = rowptr[g + 1];
  for (; e + 4 <= e1; e += 4) {
    int c0 = col[e], c1 = col[e + 1], c2 = col[e + 2], c3 = col[e + 3];
    float w0 = wgt[e], w1 = wgt[e + 1], w2 = wgt[e + 2], w3 = wgt[e + 3];
    float4 v0 = in4[(size_t)c0 * 32 + lane];
    float4 v1 = in4[(size_t)c1 * 32 + lane];
    float4 v2 = in4[(size_t)c2 * 32 + lane];
    float4 v3 = in4[(size_t)c3 * 32 + lane];
    acc.x += w0 * v0.x; acc.y += w0 * v0.y; acc.z += w0 * v0.z; acc.w += w0 * v0.w;
    acc.x += w1 * v1.x; acc.y += w1 * v1.y; acc.z += w1 * v1.z; acc.w += w1 * v1.w;
    acc.x += w2 * v2.x; acc.y += w2 * v2.y; acc.z += w2 * v2.z; acc.w += w2 * v2.w;
    acc.x += w3 * v3.x; acc.y += w3 * v3.y; acc.z += w3 * v3.z; acc.w += w3 * v3.w;
  }
  for (; e < e1; ++e) {
    int c = col[e];
    float w = wgt[e];
    float4 v = in4[(size_t)c * 32 + lane];
    acc.x += w * v.x; acc.y += w * v.y; acc.z += w * v.z; acc.w += w * v.w;
  }
  ((float4*)out)[g * 32 + lane] = acc;
}

// ---- prep: transpose each 128x128 weight to f16 [col][136] ----
__global__ __launch_bounds__(128) void k_prep(const float* __restrict__ W_low,
                                              const float* __restrict__ W_band,
                                              const float* __restrict__ W_mlp,
                                              _Float16* __restrict__ WT) {
  int m = blockIdx.x;           // 0..6 channels, 7..8 mlp chunks
  int colc = threadIdx.x;       // 0..127
  const float* src;
  if (m < 4)      src = W_low + m * 16384;
  else if (m < 7) src = W_band + (m - 4) * 16384;
  else            src = W_mlp + (m - 7) * 16384;
  _Float16* dst = WT + (size_t)m * 128 * 136;
  for (int k = 0; k < 128; ++k)
    dst[colc * 136 + k] = (_Float16)src[k * 128 + colc];
}

// ---- fused MFMA: 7-channel GEMM + attention + MLP ----
__global__ __launch_bounds__(256) void k_fused(
    const float* __restrict__ a0, const float* __restrict__ a1,
    const float* __restrict__ a2, const float* __restrict__ a4,
    const _Float16* __restrict__ WT,
    const float* __restrict__ b_low, const float* __restrict__ b_band,
    const float* __restrict__ apre_l, const float* __restrict__ ach_l,
    const float* __restrict__ apre_b, const float* __restrict__ ach_b,
    const float* __restrict__ b_mlp, float* __restrict__ out) {
  __shared__ _Float16 sW[128][136];   // B matrix, [col][k] padded   34816 B
  __shared__ _Float16 sH[7][TM][136]; // channel outputs             30464 B
  __shared__ _Float16 sV[TM][264];    // MLP input [node][256] pad    8448 B

  const int tid = threadIdx.x;
  const int wid = tid >> 6;
  const int lane = tid & 63;
  const int mrow = lane & 15;   // row within 16-tile / out col within tile
  const int kg = lane >> 4;     // k-group 0..3
  const int node0 = blockIdx.x * TM;
  const int colw = wid * 32;    // wave's 32-col slice

  // ---------- 7 channel GEMMs ----------
  for (int c = 0; c < 7; ++c) {
    const uint4* wsrc = (const uint4*)(WT + (size_t)c * (128 * 136));
    uint4* wdst = (uint4*)&sW[0][0];
    for (int i = tid; i < 2176; i += 256) wdst[i] = wsrc[i];
    __syncthreads();

    const float *pa, *pb;
    switch (c) {
      case 0: pa = a0; pb = nullptr; break;
      case 1: pa = a1; pb = nullptr; break;
      case 2: pa = a2; pb = nullptr; break;
      case 3: pa = a4; pb = nullptr; break;
      case 4: pa = a0; pb = a1; break;
      case 5: pa = a1; pb = a2; break;
      default: pa = a2; pb = a4; break;
    }
    const float4* pA = (const float4*)(pa + (size_t)(node0 + mrow) * 128);
    const float4* pB = pb ? (const float4*)(pb + (size_t)(node0 + mrow) * 128)
                          : (const float4*)nullptr;
    half8v afr[4];
#pragma unroll
    for (int ks = 0; ks < 4; ++ks) {
      float4 lo = pA[ks * 8 + kg];
      float4 hi = pA[ks * 8 + 4 + kg];
      if (pb) {
        float4 l2 = pB[ks * 8 + kg], h2 = pB[ks * 8 + 4 + kg];
        lo.x -= l2.x; lo.y -= l2.y; lo.z -= l2.z; lo.w -= l2.w;
        hi.x -= h2.x; hi.y -= h2.y; hi.z -= h2.z; hi.w -= h2.w;
      }
      half8v f;
      f[0] = (_Float16)lo.x; f[1] = (_Float16)lo.y;
      f[2] = (_Float16)lo.z; f[3] = (_Float16)lo.w;
      f[4] = (_Float16)hi.x; f[5] = (_Float16)hi.y;
      f[6] = (_Float16)hi.z; f[7] = (_Float16)hi.w;
      afr[ks] = f;
    }
    f32x4 acc0 = {0.f, 0.f, 0.f, 0.f}, acc1 = {0.f, 0.f, 0.f, 0.f};
#pragma unroll
    for (int ks = 0; ks < 4; ++ks) {
      int koff = ks * 32 + 4 * kg;
      half4v b0a = *(const half4v*)&sW[colw + mrow][koff];
      half4v b0b = *(const half4v*)&sW[colw + mrow][koff + 16];
      half4v b1a = *(const half4v*)&sW[colw + 16 + mrow][koff];
      half4v b1b = *(const half4v*)&sW[colw + 16 + mrow][koff + 16];
      half8v bf0 = __builtin_shufflevector(b0a, b0b, 0, 1, 2, 3, 4, 5, 6, 7);
      half8v bf1 = __builtin_shufflevector(b1a, b1b, 0, 1, 2, 3, 4, 5, 6, 7);
      acc0 = __builtin_amdgcn_mfma_f32_16x16x32_f16(afr[ks], bf0, acc0, 0, 0, 0);
      acc1 = __builtin_amdgcn_mfma_f32_16x16x32_f16(afr[ks], bf1, acc1, 0, 0, 0);
    }
    const float* bias = (c < 4) ? (b_low + c * 128) : (b_band + (c - 4) * 128);
    float bv0 = bias[colw + mrow];
    float bv1 = bias[colw + 16 + mrow];
#pragma unroll
    for (int r = 0; r < 4; ++r) {
      sH[c][4 * kg + r][colw + mrow] = (_Float16)(acc0[r] + bv0);
      sH[c][4 * kg + r][colw + 16 + mrow] = (_Float16)(acc1[r] + bv1);
    }
    __syncthreads();
  }

  // ---------- attention: 16 threads per node, 8 cols each ----------
  {
    const int n = tid >> 4;
    const int sub = tid & 15;
    const int cb = sub * 8;
    float apl[8], acl[8], apb[8], acb[8];
#pragma unroll
    for (int j = 0; j < 8; ++j) {
      apl[j] = apre_l[cb + j]; acl[j] = ach_l[cb + j];
      apb[j] = apre_b[cb + j]; acb[j] = ach_b[cb + j];
    }
    float dpl = 0.f, dpb = 0.f;
    float sarr[7];
#pragma unroll
    for (int c = 0; c < 7; ++c) {
      float sp = 0.f, sc = 0.f;
#pragma unroll
      for (int j = 0; j < 8; ++j) {
        float h = (float)sH[c][n][cb + j];
        float r = relu(h);
        if (c < 4) { sp += r * apl[j]; sc += r * acl[j]; }
        else       { sp += r * apb[j]; sc += r * acb[j]; }
      }
      if (c < 4) dpl += sp; else dpb += sp;
      sarr[c] = sc;
    }
    dpl *= 0.25f;
    dpb *= (1.0f / 3.0f);
#pragma unroll
    for (int m = 1; m <= 8; m <<= 1) {
      dpl += __shfl_xor(dpl, m);
      dpb += __shfl_xor(dpb, m);
#pragma unroll
      for (int c = 0; c < 7; ++c) sarr[c] += __shfl_xor(sarr[c], m);
    }
    float lg[7];
#pragma unroll
    for (int c = 0; c < 7; ++c)
      lg[c] = relu((c < 4 ? dpl : dpb) + sarr[c]);
    float ml = fmaxf(fmaxf(lg[0], lg[1]), fmaxf(lg[2], lg[3]));
    float e0 = expf(lg[0] - ml), e1 = expf(lg[1] - ml);
    float e2 = expf(lg[2] - ml), e3 = expf(lg[3] - ml);
    float invl = 1.0f / (e0 + e1 + e2 + e3);
    float mb = fmaxf(fmaxf(lg[4], lg[5]), lg[6]);
    float f4 = expf(lg[4] - mb), f5 = expf(lg[5] - mb), f6 = expf(lg[6] - mb);
    float invb = 1.0f / (f4 + f5 + f6);
    float al[7];
    al[0] = e0 * invl; al[1] = e1 * invl; al[2] = e2 * invl; al[3] = e3 * invl;
    al[4] = f4 * invb; al[5] = f5 * invb; al[6] = f6 * invb;
#pragma unroll
    for (int j = 0; j < 8; ++j) {
      float vl = 0.f, vb = 0.f;
#pragma unroll
      for (int c = 0; c < 4; ++c) vl += al[c] * (float)sH[c][n][cb + j];
#pragma unroll
      for (int c = 4; c < 7; ++c) vb += al[c] * (float)sH[c][n][cb + j];
      sV[n][cb + j] = (_Float16)vl;
      sV[n][128 + cb + j] = (_Float16)vb;
    }
  }
  __syncthreads();

  // ---------- MLP: [TM,256] @ [256,128] via 2 staged chunks ----------
  f32x4 m0 = {0.f, 0.f, 0.f, 0.f}, m1 = {0.f, 0.f, 0.f, 0.f};
#pragma unroll
  for (int hh = 0; hh < 2; ++hh) {
    const uint4* wsrc = (const uint4*)(WT + (size_t)(7 + hh) * (128 * 136));
    uint4* wdst = (uint4*)&sW[0][0];
    for (int i = tid; i < 2176; i += 256) wdst[i] = wsrc[i];
    __syncthreads();
#pragma unroll
    for (int ks = 0; ks < 4; ++ks) {
      int ka = hh * 128 + ks * 32 + 4 * kg;
      half4v aa = *(const half4v*)&sV[mrow][ka];
      half4v ab = *(const half4v*)&sV[mrow][ka + 16];
      half8v af = __builtin_shufflevector(aa, ab, 0, 1, 2, 3, 4, 5, 6, 7);
      int kw = ks * 32 + 4 * kg;
      half4v b0a = *(const half4v*)&sW[colw + mrow][kw];
      half4v b0b = *(const half4v*)&sW[colw + mrow][kw + 16];
      half4v b1a = *(const half4v*)&sW[colw + 16 + mrow][kw];
      half4v b1b = *(const half4v*)&sW[colw + 16 + mrow][kw + 16];
      half8v bf0 = __builtin_shufflevector(b0a, b0b, 0, 1, 2, 3, 4, 5, 6, 7);
      half8v bf1 = __builtin_shufflevector(b1a, b1b, 0, 1, 2, 3, 4, 5, 6, 7);
      m0 = __builtin_amdgcn_mfma_f32_16x16x32_f16(af, bf0, m0, 0, 0, 0);
      m1 = __builtin_amdgcn_mfma_f32_16x16x32_f16(af, bf1, m1, 0, 0, 0);
    }
    __syncthreads();
  }
  float bm0 = b_mlp[colw + mrow];
  float bm1 = b_mlp[colw + 16 + mrow];
#pragma unroll
  for (int r = 0; r < 4; ++r) {
    out[(size_t)(node0 + 4 * kg + r) * 128 + colw + mrow] = m0[r] + bm0;
    out[(size_t)(node0 + 4 * kg + r) * 128 + colw + 16 + mrow] = m1[r] + bm1;
  }
}

extern "C" void kernel_launch(void* const* d_in, const int* in_sizes, int n_in,
                              void* d_out, int out_size, void* d_ws, size_t ws_size,
                              hipStream_t stream) {
  const float* x      = (const float*)d_in[0];
  const int* ei       = (const int*)d_in[1];
  const float* W_low  = (const float*)d_in[2];
  const float* b_low  = (const float*)d_in[3];
  const float* W_band = (const float*)d_in[4];
  const float* b_band = (const float*)d_in[5];
  const float* apre_l = (const float*)d_in[6];
  const float* ach_l  = (const float*)d_in[7];
  const float* apre_b = (const float*)d_in[8];
  const float* ach_b  = (const float*)d_in[9];
  const float* W_mlp  = (const float*)d_in[10];
  const float* b_mlp  = (const float*)d_in[11];
  float* out = (float*)d_out;

  char* ws = (char*)d_ws;
  size_t off = 0;
  auto take = [&](size_t bytes) -> void* {
    void* p = ws + off;
    off = (off + bytes + 255) & ~(size_t)255;
    return p;
  };
  int*   deg    = (int*)take((size_t)NN * 4);
  int*   fill   = (int*)take((size_t)NN * 4);
  size_t zero_bytes = off;  // deg + fill region
  float* dinv   = (float*)take((size_t)NN * 4);
  int*   rowptr = (int*)take((size_t)(NN + 1) * 4);
  int*   col    = (int*)take((size_t)NE * 4);
  float* wgt    = (float*)take((size_t)NE * 4);
  float* a1v    = (float*)take((size_t)NN * 128 * 4);
  float* a2v    = (float*)take((size_t)NN * 128 * 4);
  float* a3v    = (float*)take((size_t)NN * 128 * 4);
  float* a4v    = (float*)take((size_t)NN * 128 * 4);
  _Float16* WT  = (_Float16*)take((size_t)9 * 128 * 136 * 2);
  (void)ws_size; (void)in_sizes; (void)n_in; (void)out_size;

  hipMemsetAsync(d_ws, 0, zero_bytes, stream);
  k_prep<<<9, 128, 0, stream>>>(W_low, W_band, W_mlp, WT);
  k_deg<<<(NE + 255) / 256, 256, 0, stream>>>(ei, deg);
  k_dinv<<<(NN + 255) / 256, 256, 0, stream>>>(deg, dinv);
  k_scan<<<1, 1024, 0, stream>>>(deg, rowptr);
  k_fill<<<(NE + 255) / 256, 256, 0, stream>>>(ei, dinv, rowptr, fill, col, wgt);
  k_hop<<<(NN + 7) / 8, 256, 0, stream>>>(x,   a1v, rowptr, col, wgt);
  k_hop<<<(NN + 7) / 8, 256, 0, stream>>>(a1v, a2v, rowptr, col, wgt);
  k_hop<<<(NN + 7) / 8, 256, 0, stream>>>(a2v, a3v, rowptr, col, wgt);
  k_hop<<<(NN + 7) / 8, 256, 0, stream>>>(a3v, a4v, rowptr, col, wgt);
  k_fused<<<NN / TM, 256, 0, stream>>>(x, a1v, a2v, a4v, WT, b_low, b_band,
                                       apre_l, ach_l, apre_b, ach_b, b_mlp, out);
}

// Round 4
// 552.158 us; speedup vs baseline: 2.1387x; 1.1352x over previous
//
#include <hip/hip_runtime.h>
#include <math.h>

#define NN 50000
#define NE 800000
#define TM 16

typedef _Float16 half4v __attribute__((ext_vector_type(4)));
typedef _Float16 half8v __attribute__((ext_vector_type(8)));
typedef float f32x4 __attribute__((ext_vector_type(4)));

__device__ __forceinline__ float relu(float v) { return fmaxf(v, 0.0f); }

// ---- degree count over dst ----
__global__ __launch_bounds__(256) void k_deg(const int* __restrict__ ei,
                                             int* __restrict__ deg) {
  int e = blockIdx.x * 256 + threadIdx.x;
  if (e < NE) atomicAdd(&deg[ei[NE + e]], 1);
}

// ---- d^-1/2 ----
__global__ __launch_bounds__(256) void k_dinv(const int* __restrict__ deg,
                                              float* __restrict__ dinv) {
  int i = blockIdx.x * 256 + threadIdx.x;
  if (i < NN) {
    int d = deg[i];
    dinv[i] = d > 0 ? 1.0f / sqrtf((float)d) : 0.0f;
  }
}

// ---- exclusive scan of deg -> rowptr (single 1024-thread block) ----
__global__ __launch_bounds__(1024) void k_scan(const int* __restrict__ deg,
                                               int* __restrict__ rowptr) {
  __shared__ int swave[16];
  __shared__ int scarry;
  const int tid = threadIdx.x;
  const int lane = tid & 63;
  const int wid = tid >> 6;
  if (tid == 0) scarry = 0;
  __syncthreads();
  for (int base = 0; base < NN; base += 1024) {
    int i = base + tid;
    int v = (i < NN) ? deg[i] : 0;
    int sum = v;
#pragma unroll
    for (int off = 1; off < 64; off <<= 1) {
      int t = __shfl_up(sum, off);
      if (lane >= off) sum += t;
    }
    if (lane == 63) swave[wid] = sum;
    __syncthreads();
    int wbase = 0;
    for (int w = 0; w < wid; ++w) wbase += swave[w];
    int carry = scarry;
    if (i < NN) rowptr[i] = carry + wbase + sum - v;
    __syncthreads();
    if (tid == 1023) scarry = carry + wbase + sum;
    __syncthreads();
  }
  if (tid == 0) rowptr[NN] = scarry;
}

// ---- CSR fill + edge weights ----
__global__ __launch_bounds__(256) void k_fill(const int* __restrict__ ei,
                                              const float* __restrict__ dinv,
                                              const int* __restrict__ rowptr,
                                              int* __restrict__ fill,
                                              int* __restrict__ col,
                                              float* __restrict__ wgt) {
  int e = blockIdx.x * 256 + threadIdx.x;
  if (e < NE) {
    int s = ei[e];
    int d = ei[NE + e];
    float w = dinv[s] * dinv[d] * 0.5f;
    int pos = rowptr[d] + atomicAdd(&fill[d], 1);
    col[pos] = s;
    wgt[pos] = w;
  }
}

// ---- x (f32) -> xh (f16) ----
__global__ __launch_bounds__(256) void k_x2h(const float* __restrict__ x,
                                             _Float16* __restrict__ xh) {
  int i = blockIdx.x * 256 + threadIdx.x;
  if (i < NN * 32) {
    float4 v = ((const float4*)x)[i];
    half4v h;
    h[0] = (_Float16)v.x; h[1] = (_Float16)v.y;
    h[2] = (_Float16)v.z; h[3] = (_Float16)v.w;
    ((half4v*)xh)[i] = h;
  }
}

// ---- one hop on f16 rows, f32 accumulate: out = 0.5*in + sum w_e*in[col] ----
__global__ __launch_bounds__(256) void k_hop16(const _Float16* __restrict__ in,
                                               _Float16* __restrict__ out,
                                               const int* __restrict__ rowptr,
                                               const int* __restrict__ col,
                                               const float* __restrict__ wgt) {
  int g = (blockIdx.x * 256 + threadIdx.x) >> 5;  // node, 32 threads/node
  int lane = threadIdx.x & 31;
  if (g >= NN) return;
  const half4v* in4 = (const half4v*)in;  // 8B per lane, 256B per row
  half4v a = in4[(size_t)g * 32 + lane];
  float ax = 0.5f * (float)a[0], ay = 0.5f * (float)a[1];
  float az = 0.5f * (float)a[2], aw = 0.5f * (float)a[3];
  int e = rowptr[g], e1 = rowptr[g + 1];
  for (; e + 4 <= e1; e += 4) {
    int c0 = col[e], c1 = col[e + 1], c2 = col[e + 2], c3 = col[e + 3];
    float w0 = wgt[e], w1 = wgt[e + 1], w2 = wgt[e + 2], w3 = wgt[e + 3];
    half4v v0 = in4[(size_t)c0 * 32 + lane];
    half4v v1 = in4[(size_t)c1 * 32 + lane];
    half4v v2 = in4[(size_t)c2 * 32 + lane];
    half4v v3 = in4[(size_t)c3 * 32 + lane];
    ax += w0 * (float)v0[0]; ay += w0 * (float)v0[1];
    az += w0 * (float)v0[2]; aw += w0 * (float)v0[3];
    ax += w1 * (float)v1[0]; ay += w1 * (float)v1[1];
    az += w1 * (float)v1[2]; aw += w1 * (float)v1[3];
    ax += w2 * (float)v2[0]; ay += w2 * (float)v2[1];
    az += w2 * (float)v2[2]; aw += w2 * (float)v2[3];
    ax += w3 * (float)v3[0]; ay += w3 * (float)v3[1];
    az += w3 * (float)v3[2]; aw += w3 * (float)v3[3];
  }
  for (; e < e1; ++e) {
    int c = col[e];
    float w = wgt[e];
    half4v v = in4[(size_t)c * 32 + lane];
    ax += w * (float)v[0]; ay += w * (float)v[1];
    az += w * (float)v[2]; aw += w * (float)v[3];
  }
  half4v r;
  r[0] = (_Float16)ax; r[1] = (_Float16)ay;
  r[2] = (_Float16)az; r[3] = (_Float16)aw;
  ((half4v*)out)[(size_t)g * 32 + lane] = r;
}

// ---- prep: transpose each 128x128 weight to f16 [col][128] ----
__global__ __launch_bounds__(128) void k_prep(const float* __restrict__ W_low,
                                              const float* __restrict__ W_band,
                                              const float* __restrict__ W_mlp,
                                              _Float16* __restrict__ WT) {
  int m = blockIdx.x;           // 0..6 channels, 7..8 mlp chunks
  int colc = threadIdx.x;       // 0..127
  const float* src;
  if (m < 4)      src = W_low + m * 16384;
  else if (m < 7) src = W_band + (m - 4) * 16384;
  else            src = W_mlp + (m - 7) * 16384;
  _Float16* dst = WT + (size_t)m * 16384;
  for (int k = 0; k < 128; ++k)
    dst[colc * 128 + k] = (_Float16)src[k * 128 + colc];
}

// ---- fused MFMA: 7-channel GEMM + attention + MLP; weights from L2 ----
__global__ __launch_bounds__(256, 3) void k_fused(
    const _Float16* __restrict__ xh, const _Float16* __restrict__ a1,
    const _Float16* __restrict__ a2, const _Float16* __restrict__ a4,
    const _Float16* __restrict__ WT,
    const float* __restrict__ b_low, const float* __restrict__ b_band,
    const float* __restrict__ apre_l, const float* __restrict__ ach_l,
    const float* __restrict__ apre_b, const float* __restrict__ ach_b,
    const float* __restrict__ b_mlp, float* __restrict__ out) {
  __shared__ _Float16 sH[7][TM][136]; // channel outputs  30464 B
  __shared__ _Float16 sV[TM][264];    // MLP input         8448 B

  const int tid = threadIdx.x;
  const int wid = tid >> 6;
  const int lane = tid & 63;
  const int mrow = lane & 15;   // node row in tile / out col in 16-tile
  const int kg = lane >> 4;     // k-group 0..3
  const int node0 = blockIdx.x * TM;
  const int colw = wid * 32;    // wave's 32-col slice

  // ---- A fragments for the 4 base aggregates (held in registers) ----
  half8v base[4][4];  // [array][ks]
  {
    const _Float16* arrs[4] = {xh, a1, a2, a4};
#pragma unroll
    for (int t = 0; t < 4; ++t) {
      const _Float16* p = arrs[t] + (size_t)(node0 + mrow) * 128;
#pragma unroll
      for (int ks = 0; ks < 4; ++ks) {
        half4v lo = *(const half4v*)&p[ks * 32 + 4 * kg];
        half4v hi = *(const half4v*)&p[ks * 32 + 4 * kg + 16];
        base[t][ks] = __builtin_shufflevector(lo, hi, 0, 1, 2, 3, 4, 5, 6, 7);
      }
    }
  }

  // ---- 7 channel GEMMs, B direct from global (L2-hot) ----
#pragma unroll
  for (int c = 0; c < 7; ++c) {
    const int ia = (c < 4) ? c : (c - 4);
    const int ib = (c < 4) ? -1 : (c - 3);
    const _Float16* w0 = WT + (size_t)c * 16384 + (size_t)(colw + mrow) * 128;
    const _Float16* w1 = w0 + 16 * 128;
    f32x4 acc0 = {0.f, 0.f, 0.f, 0.f}, acc1 = {0.f, 0.f, 0.f, 0.f};
#pragma unroll
    for (int ks = 0; ks < 4; ++ks) {
      half8v af = (ib < 0) ? base[ia][ks] : (base[ia][ks] - base[ib][ks]);
      int ko = ks * 32 + 4 * kg;
      half4v b0a = *(const half4v*)&w0[ko];
      half4v b0b = *(const half4v*)&w0[ko + 16];
      half4v b1a = *(const half4v*)&w1[ko];
      half4v b1b = *(const half4v*)&w1[ko + 16];
      half8v bf0 = __builtin_shufflevector(b0a, b0b, 0, 1, 2, 3, 4, 5, 6, 7);
      half8v bf1 = __builtin_shufflevector(b1a, b1b, 0, 1, 2, 3, 4, 5, 6, 7);
      acc0 = __builtin_amdgcn_mfma_f32_16x16x32_f16(af, bf0, acc0, 0, 0, 0);
      acc1 = __builtin_amdgcn_mfma_f32_16x16x32_f16(af, bf1, acc1, 0, 0, 0);
    }
    const float* bias = (c < 4) ? (b_low + c * 128) : (b_band + (c - 4) * 128);
    float bv0 = bias[colw + mrow];
    float bv1 = bias[colw + 16 + mrow];
#pragma unroll
    for (int r = 0; r < 4; ++r) {
      sH[c][4 * kg + r][colw + mrow] = (_Float16)(acc0[r] + bv0);
      sH[c][4 * kg + r][colw + 16 + mrow] = (_Float16)(acc1[r] + bv1);
    }
  }
  __syncthreads();

  // ---- attention: 16 threads per node, 8 cols each ----
  {
    const int n = tid >> 4;
    const int cb = (tid & 15) * 8;
    float apl[8], acl[8], apb[8], acb[8];
#pragma unroll
    for (int j = 0; j < 8; ++j) {
      apl[j] = apre_l[cb + j]; acl[j] = ach_l[cb + j];
      apb[j] = apre_b[cb + j]; acb[j] = ach_b[cb + j];
    }
    float dpl = 0.f, dpb = 0.f;
    float sarr[7];
#pragma unroll
    for (int c = 0; c < 7; ++c) {
      float sp = 0.f, sc = 0.f;
#pragma unroll
      for (int j = 0; j < 8; ++j) {
        float h = (float)sH[c][n][cb + j];
        float r = relu(h);
        if (c < 4) { sp += r * apl[j]; sc += r * acl[j]; }
        else       { sp += r * apb[j]; sc += r * acb[j]; }
      }
      if (c < 4) dpl += sp; else dpb += sp;
      sarr[c] = sc;
    }
    dpl *= 0.25f;
    dpb *= (1.0f / 3.0f);
#pragma unroll
    for (int m = 1; m <= 8; m <<= 1) {
      dpl += __shfl_xor(dpl, m);
      dpb += __shfl_xor(dpb, m);
#pragma unroll
      for (int c = 0; c < 7; ++c) sarr[c] += __shfl_xor(sarr[c], m);
    }
    float lg[7];
#pragma unroll
    for (int c = 0; c < 7; ++c)
      lg[c] = relu((c < 4 ? dpl : dpb) + sarr[c]);
    float ml = fmaxf(fmaxf(lg[0], lg[1]), fmaxf(lg[2], lg[3]));
    float e0 = expf(lg[0] - ml), e1 = expf(lg[1] - ml);
    float e2 = expf(lg[2] - ml), e3 = expf(lg[3] - ml);
    float invl = 1.0f / (e0 + e1 + e2 + e3);
    float mb = fmaxf(fmaxf(lg[4], lg[5]), lg[6]);
    float f4 = expf(lg[4] - mb), f5 = expf(lg[5] - mb), f6 = expf(lg[6] - mb);
    float invb = 1.0f / (f4 + f5 + f6);
    float al[7];
    al[0] = e0 * invl; al[1] = e1 * invl; al[2] = e2 * invl; al[3] = e3 * invl;
    al[4] = f4 * invb; al[5] = f5 * invb; al[6] = f6 * invb;
    half8v vl8, vb8;
#pragma unroll
    for (int j = 0; j < 8; ++j) {
      float vl = 0.f, vb = 0.f;
#pragma unroll
      for (int c = 0; c < 4; ++c) vl += al[c] * (float)sH[c][n][cb + j];
#pragma unroll
      for (int c = 4; c < 7; ++c) vb += al[c] * (float)sH[c][n][cb + j];
      vl8[j] = (_Float16)vl;
      vb8[j] = (_Float16)vb;
    }
    *(half8v*)&sV[n][cb] = vl8;
    *(half8v*)&sV[n][128 + cb] = vb8;
  }
  __syncthreads();

  // ---- MLP: [TM,256] @ [256,128], B direct from global ----
  f32x4 m0 = {0.f, 0.f, 0.f, 0.f}, m1 = {0.f, 0.f, 0.f, 0.f};
#pragma unroll
  for (int hh = 0; hh < 2; ++hh) {
    const _Float16* w0 = WT + (size_t)(7 + hh) * 16384 + (size_t)(colw + mrow) * 128;
    const _Float16* w1 = w0 + 16 * 128;
#pragma unroll
    for (int ks = 0; ks < 4; ++ks) {
      int ka = hh * 128 + ks * 32 + 4 * kg;
      half4v aa = *(const half4v*)&sV[mrow][ka];
      half4v ab = *(const half4v*)&sV[mrow][ka + 16];
      half8v af = __builtin_shufflevector(aa, ab, 0, 1, 2, 3, 4, 5, 6, 7);
      int ko = ks * 32 + 4 * kg;
      half4v b0a = *(const half4v*)&w0[ko];
      half4v b0b = *(const half4v*)&w0[ko + 16];
      half4v b1a = *(const half4v*)&w1[ko];
      half4v b1b = *(const half4v*)&w1[ko + 16];
      half8v bf0 = __builtin_shufflevector(b0a, b0b, 0, 1, 2, 3, 4, 5, 6, 7);
      half8v bf1 = __builtin_shufflevector(b1a, b1b, 0, 1, 2, 3, 4, 5, 6, 7);
      m0 = __builtin_amdgcn_mfma_f32_16x16x32_f16(af, bf0, m0, 0, 0, 0);
      m1 = __builtin_amdgcn_mfma_f32_16x16x32_f16(af, bf1, m1, 0, 0, 0);
    }
  }
  float bm0 = b_mlp[colw + mrow];
  float bm1 = b_mlp[colw + 16 + mrow];
#pragma unroll
  for (int r = 0; r < 4; ++r) {
    out[(size_t)(node0 + 4 * kg + r) * 128 + colw + mrow] = m0[r] + bm0;
    out[(size_t)(node0 + 4 * kg + r) * 128 + colw + 16 + mrow] = m1[r] + bm1;
  }
}

extern "C" void kernel_launch(void* const* d_in, const int* in_sizes, int n_in,
                              void* d_out, int out_size, void* d_ws, size_t ws_size,
                              hipStream_t stream) {
  const float* x      = (const float*)d_in[0];
  const int* ei       = (const int*)d_in[1];
  const float* W_low  = (const float*)d_in[2];
  const float* b_low  = (const float*)d_in[3];
  const float* W_band = (const float*)d_in[4];
  const float* b_band = (const float*)d_in[5];
  const float* apre_l = (const float*)d_in[6];
  const float* ach_l  = (const float*)d_in[7];
  const float* apre_b = (const float*)d_in[8];
  const float* ach_b  = (const float*)d_in[9];
  const float* W_mlp  = (const float*)d_in[10];
  const float* b_mlp  = (const float*)d_in[11];
  float* out = (float*)d_out;

  char* ws = (char*)d_ws;
  size_t off = 0;
  auto take = [&](size_t bytes) -> void* {
    void* p = ws + off;
    off = (off + bytes + 255) & ~(size_t)255;
    return p;
  };
  int*   deg    = (int*)take((size_t)NN * 4);
  int*   fill   = (int*)take((size_t)NN * 4);
  size_t zero_bytes = off;  // deg + fill region
  float* dinv   = (float*)take((size_t)NN * 4);
  int*   rowptr = (int*)take((size_t)(NN + 1) * 4);
  int*   col    = (int*)take((size_t)NE * 4);
  float* wgt    = (float*)take((size_t)NE * 4);
  _Float16* xh  = (_Float16*)take((size_t)NN * 128 * 2);
  _Float16* a1h = (_Float16*)take((size_t)NN * 128 * 2);
  _Float16* a2h = (_Float16*)take((size_t)NN * 128 * 2);
  _Float16* a3h = (_Float16*)take((size_t)NN * 128 * 2);
  _Float16* a4h = (_Float16*)take((size_t)NN * 128 * 2);
  _Float16* WT  = (_Float16*)take((size_t)9 * 16384 * 2);
  (void)ws_size; (void)in_sizes; (void)n_in; (void)out_size;

  hipMemsetAsync(d_ws, 0, zero_bytes, stream);
  k_prep<<<9, 128, 0, stream>>>(W_low, W_band, W_mlp, WT);
  k_x2h<<<(NN * 32 + 255) / 256, 256, 0, stream>>>(x, xh);
  k_deg<<<(NE + 255) / 256, 256, 0, stream>>>(ei, deg);
  k_dinv<<<(NN + 255) / 256, 256, 0, stream>>>(deg, dinv);
  k_scan<<<1, 1024, 0, stream>>>(deg, rowptr);
  k_fill<<<(NE + 255) / 256, 256, 0, stream>>>(ei, dinv, rowptr, fill, col, wgt);
  k_hop16<<<(NN + 7) / 8, 256, 0, stream>>>(xh,  a1h, rowptr, col, wgt);
  k_hop16<<<(NN + 7) / 8, 256, 0, stream>>>(a1h, a2h, rowptr, col, wgt);
  k_hop16<<<(NN + 7) / 8, 256, 0, stream>>>(a2h, a3h, rowptr, col, wgt);
  k_hop16<<<(NN + 7) / 8, 256, 0, stream>>>(a3h, a4h, rowptr, col, wgt);
  k_fused<<<NN / TM, 256, 0, stream>>>(xh, a1h, a2h, a4h, WT, b_low, b_band,
                                       apre_l, ach_l, apre_b, ach_b, b_mlp, out);
}

// Round 5
// 371.162 us; speedup vs baseline: 3.1816x; 1.4876x over previous
//
#include <hip/hip_runtime.h>
#include <math.h>

#define NN 50000
#define NE 800000
#define TM 16

typedef _Float16 half4v __attribute__((ext_vector_type(4)));
typedef _Float16 half8v __attribute__((ext_vector_type(8)));
typedef float f32x4 __attribute__((ext_vector_type(4)));

__device__ __forceinline__ float relu(float v) { return fmaxf(v, 0.0f); }

// ---- degree count over dst ----
__global__ __launch_bounds__(256) void k_deg(const int* __restrict__ ei,
                                             int* __restrict__ deg) {
  int e = blockIdx.x * 256 + threadIdx.x;
  if (e < NE) atomicAdd(&deg[ei[NE + e]], 1);
}

// ---- d^-1/2 ----
__global__ __launch_bounds__(256) void k_dinv(const int* __restrict__ deg,
                                              float* __restrict__ dinv) {
  int i = blockIdx.x * 256 + threadIdx.x;
  if (i < NN) {
    int d = deg[i];
    dinv[i] = d > 0 ? 1.0f / sqrtf((float)d) : 0.0f;
  }
}

// ---- exclusive scan of deg -> rowptr (single 1024-thread block) ----
__global__ __launch_bounds__(1024) void k_scan(const int* __restrict__ deg,
                                               int* __restrict__ rowptr) {
  __shared__ int swave[16];
  __shared__ int scarry;
  const int tid = threadIdx.x;
  const int lane = tid & 63;
  const int wid = tid >> 6;
  if (tid == 0) scarry = 0;
  __syncthreads();
  for (int base = 0; base < NN; base += 1024) {
    int i = base + tid;
    int v = (i < NN) ? deg[i] : 0;
    int sum = v;
#pragma unroll
    for (int off = 1; off < 64; off <<= 1) {
      int t = __shfl_up(sum, off);
      if (lane >= off) sum += t;
    }
    if (lane == 63) swave[wid] = sum;
    __syncthreads();
    int wbase = 0;
    for (int w = 0; w < wid; ++w) wbase += swave[w];
    int carry = scarry;
    if (i < NN) rowptr[i] = carry + wbase + sum - v;
    __syncthreads();
    if (tid == 1023) scarry = carry + wbase + sum;
    __syncthreads();
  }
  if (tid == 0) rowptr[NN] = scarry;
}

// ---- CSR fill + edge weights ----
__global__ __launch_bounds__(256) void k_fill(const int* __restrict__ ei,
                                              const float* __restrict__ dinv,
                                              const int* __restrict__ rowptr,
                                              int* __restrict__ fill,
                                              int* __restrict__ col,
                                              float* __restrict__ wgt) {
  int e = blockIdx.x * 256 + threadIdx.x;
  if (e < NE) {
    int s = ei[e];
    int d = ei[NE + e];
    float w = dinv[s] * dinv[d] * 0.5f;
    int pos = rowptr[d] + atomicAdd(&fill[d], 1);
    col[pos] = s;
    wgt[pos] = w;
  }
}

// ---- x (f32) -> xh (f16) ----
__global__ __launch_bounds__(256) void k_x2h(const float* __restrict__ x,
                                             _Float16* __restrict__ xh) {
  int i = blockIdx.x * 256 + threadIdx.x;
  if (i < NN * 32) {
    float4 v = ((const float4*)x)[i];
    half4v h;
    h[0] = (_Float16)v.x; h[1] = (_Float16)v.y;
    h[2] = (_Float16)v.z; h[3] = (_Float16)v.w;
    ((half4v*)xh)[i] = h;
  }
}

// ---- one hop: 16 lanes/node, 16B row chunks, f32 accumulate ----
__global__ __launch_bounds__(256) void k_hop16(const _Float16* __restrict__ in,
                                               _Float16* __restrict__ out,
                                               const int* __restrict__ rowptr,
                                               const int* __restrict__ col,
                                               const float* __restrict__ wgt) {
  int g = (blockIdx.x * 256 + threadIdx.x) >> 4;  // node, 16 threads/node
  int lane = threadIdx.x & 15;
  if (g >= NN) return;
  const half8v* in8 = (const half8v*)in;  // 16B per lane, 256B per row
  half8v a = in8[(size_t)g * 16 + lane];
  float acc[8];
#pragma unroll
  for (int j = 0; j < 8; ++j) acc[j] = 0.5f * (float)a[j];
  int e = rowptr[g], e1 = rowptr[g + 1];
  for (; e + 4 <= e1; e += 4) {
    int c0 = col[e], c1 = col[e + 1], c2 = col[e + 2], c3 = col[e + 3];
    float w0 = wgt[e], w1 = wgt[e + 1], w2 = wgt[e + 2], w3 = wgt[e + 3];
    half8v v0 = in8[(size_t)c0 * 16 + lane];
    half8v v1 = in8[(size_t)c1 * 16 + lane];
    half8v v2 = in8[(size_t)c2 * 16 + lane];
    half8v v3 = in8[(size_t)c3 * 16 + lane];
#pragma unroll
    for (int j = 0; j < 8; ++j)
      acc[j] += w0 * (float)v0[j] + w1 * (float)v1[j] +
                w2 * (float)v2[j] + w3 * (float)v3[j];
  }
  for (; e < e1; ++e) {
    float w = wgt[e];
    half8v v = in8[(size_t)col[e] * 16 + lane];
#pragma unroll
    for (int j = 0; j < 8; ++j) acc[j] += w * (float)v[j];
  }
  half8v r;
#pragma unroll
  for (int j = 0; j < 8; ++j) r[j] = (_Float16)acc[j];
  ((half8v*)out)[(size_t)g * 16 + lane] = r;
}

// ---- prep: weights -> f16 fragment-order [m][ct(8)][ks(4)][lane(64)][8] ----
// Fragment for B of mfma_f32_16x16x32_f16: lane = kg*16+mcol;
// col = ct*16+mcol; elems j<4 -> k = ks*32+4*kg+j ; j>=4 -> k+16.
__global__ __launch_bounds__(256) void k_prep(const float* __restrict__ W_low,
                                              const float* __restrict__ W_band,
                                              const float* __restrict__ W_mlp,
                                              _Float16* __restrict__ WTs) {
  int m = blockIdx.x;  // 0..6 channels, 7..8 mlp chunks
  const float* src;
  if (m < 4)      src = W_low + m * 16384;
  else if (m < 7) src = W_band + (m - 4) * 16384;
  else            src = W_mlp + (m - 7) * 16384;
  _Float16* dst = WTs + (size_t)m * 16384;
  for (int s = threadIdx.x; s < 2048; s += 256) {
    int ct = s >> 8;          // col tile 0..7
    int ks = (s >> 6) & 3;    // k step 0..3
    int lane = s & 63;
    int mcol = lane & 15, kg = lane >> 4;
    int colc = ct * 16 + mcol;
    int k0 = ks * 32 + 4 * kg;
    _Float16* d = dst + (size_t)s * 8;
#pragma unroll
    for (int j = 0; j < 4; ++j) d[j] = (_Float16)src[(k0 + j) * 128 + colc];
#pragma unroll
    for (int j = 0; j < 4; ++j) d[4 + j] = (_Float16)src[(k0 + 16 + j) * 128 + colc];
  }
}

// ---- fused MFMA: 7-channel GEMM + attention + MLP; coalesced B frags ----
__global__ __launch_bounds__(256, 3) void k_fused(
    const _Float16* __restrict__ xh, const _Float16* __restrict__ a1,
    const _Float16* __restrict__ a2, const _Float16* __restrict__ a4,
    const _Float16* __restrict__ WTs,
    const float* __restrict__ b_low, const float* __restrict__ b_band,
    const float* __restrict__ apre_l, const float* __restrict__ ach_l,
    const float* __restrict__ apre_b, const float* __restrict__ ach_b,
    const float* __restrict__ b_mlp, float* __restrict__ out) {
  __shared__ _Float16 sH[7][TM][136]; // channel outputs  30464 B
  __shared__ _Float16 sV[TM][264];    // MLP input         8448 B

  const int tid = threadIdx.x;
  const int wid = tid >> 6;
  const int lane = tid & 63;
  const int mrow = lane & 15;   // node row in tile / out col in 16-tile
  const int kg = lane >> 4;     // k-group 0..3
  const int node0 = blockIdx.x * TM;
  const int colw = wid * 32;    // wave's 32-col slice (coltiles 2wid, 2wid+1)

  // ---- A fragments for the 4 base aggregates (held in registers) ----
  half8v base[4][4];  // [array][ks]
  {
    const _Float16* arrs[4] = {xh, a1, a2, a4};
#pragma unroll
    for (int t = 0; t < 4; ++t) {
      const _Float16* p = arrs[t] + (size_t)(node0 + mrow) * 128;
#pragma unroll
      for (int ks = 0; ks < 4; ++ks) {
        half4v lo = *(const half4v*)&p[ks * 32 + 4 * kg];
        half4v hi = *(const half4v*)&p[ks * 32 + 4 * kg + 16];
        base[t][ks] = __builtin_shufflevector(lo, hi, 0, 1, 2, 3, 4, 5, 6, 7);
      }
    }
  }

  // ---- 7 channel GEMMs, B frags coalesced from global (L2-hot) ----
#pragma unroll
  for (int c = 0; c < 7; ++c) {
    const int ia = (c < 4) ? c : (c - 4);
    const int ib = (c < 4) ? -1 : (c - 3);
    const _Float16* wc = WTs + (size_t)c * 16384;
    f32x4 acc0 = {0.f, 0.f, 0.f, 0.f}, acc1 = {0.f, 0.f, 0.f, 0.f};
#pragma unroll
    for (int ks = 0; ks < 4; ++ks) {
      half8v af = (ib < 0) ? base[ia][ks] : (base[ia][ks] - base[ib][ks]);
      half8v bf0 = *(const half8v*)&wc[(size_t)(2 * wid) * 2048 + ks * 512 + lane * 8];
      half8v bf1 = *(const half8v*)&wc[(size_t)(2 * wid + 1) * 2048 + ks * 512 + lane * 8];
      acc0 = __builtin_amdgcn_mfma_f32_16x16x32_f16(af, bf0, acc0, 0, 0, 0);
      acc1 = __builtin_amdgcn_mfma_f32_16x16x32_f16(af, bf1, acc1, 0, 0, 0);
    }
    const float* bias = (c < 4) ? (b_low + c * 128) : (b_band + (c - 4) * 128);
    float bv0 = bias[colw + mrow];
    float bv1 = bias[colw + 16 + mrow];
#pragma unroll
    for (int r = 0; r < 4; ++r) {
      sH[c][4 * kg + r][colw + mrow] = (_Float16)(acc0[r] + bv0);
      sH[c][4 * kg + r][colw + 16 + mrow] = (_Float16)(acc1[r] + bv1);
    }
  }
  __syncthreads();

  // ---- attention: 16 threads per node, 8 cols each ----
  {
    const int n = tid >> 4;
    const int cb = (tid & 15) * 8;
    float apl[8], acl[8], apb[8], acb[8];
#pragma unroll
    for (int j = 0; j < 8; ++j) {
      apl[j] = apre_l[cb + j]; acl[j] = ach_l[cb + j];
      apb[j] = apre_b[cb + j]; acb[j] = ach_b[cb + j];
    }
    float dpl = 0.f, dpb = 0.f;
    float sarr[7];
#pragma unroll
    for (int c = 0; c < 7; ++c) {
      float sp = 0.f, sc = 0.f;
#pragma unroll
      for (int j = 0; j < 8; ++j) {
        float h = (float)sH[c][n][cb + j];
        float r = relu(h);
        if (c < 4) { sp += r * apl[j]; sc += r * acl[j]; }
        else       { sp += r * apb[j]; sc += r * acb[j]; }
      }
      if (c < 4) dpl += sp; else dpb += sp;
      sarr[c] = sc;
    }
    dpl *= 0.25f;
    dpb *= (1.0f / 3.0f);
#pragma unroll
    for (int m = 1; m <= 8; m <<= 1) {
      dpl += __shfl_xor(dpl, m);
      dpb += __shfl_xor(dpb, m);
#pragma unroll
      for (int c = 0; c < 7; ++c) sarr[c] += __shfl_xor(sarr[c], m);
    }
    float lg[7];
#pragma unroll
    for (int c = 0; c < 7; ++c)
      lg[c] = relu((c < 4 ? dpl : dpb) + sarr[c]);
    float ml = fmaxf(fmaxf(lg[0], lg[1]), fmaxf(lg[2], lg[3]));
    float e0 = expf(lg[0] - ml), e1 = expf(lg[1] - ml);
    float e2 = expf(lg[2] - ml), e3 = expf(lg[3] - ml);
    float invl = 1.0f / (e0 + e1 + e2 + e3);
    float mb = fmaxf(fmaxf(lg[4], lg[5]), lg[6]);
    float f4 = expf(lg[4] - mb), f5 = expf(lg[5] - mb), f6 = expf(lg[6] - mb);
    float invb = 1.0f / (f4 + f5 + f6);
    float al[7];
    al[0] = e0 * invl; al[1] = e1 * invl; al[2] = e2 * invl; al[3] = e3 * invl;
    al[4] = f4 * invb; al[5] = f5 * invb; al[6] = f6 * invb;
    half8v vl8, vb8;
#pragma unroll
    for (int j = 0; j < 8; ++j) {
      float vl = 0.f, vb = 0.f;
#pragma unroll
      for (int c = 0; c < 4; ++c) vl += al[c] * (float)sH[c][n][cb + j];
#pragma unroll
      for (int c = 4; c < 7; ++c) vb += al[c] * (float)sH[c][n][cb + j];
      vl8[j] = (_Float16)vl;
      vb8[j] = (_Float16)vb;
    }
    *(half8v*)&sV[n][cb] = vl8;
    *(half8v*)&sV[n][128 + cb] = vb8;
  }
  __syncthreads();

  // ---- MLP: [TM,256] @ [256,128], coalesced B frags ----
  f32x4 m0 = {0.f, 0.f, 0.f, 0.f}, m1 = {0.f, 0.f, 0.f, 0.f};
#pragma unroll
  for (int hh = 0; hh < 2; ++hh) {
    const _Float16* wm = WTs + (size_t)(7 + hh) * 16384;
#pragma unroll
    for (int ks = 0; ks < 4; ++ks) {
      int ka = hh * 128 + ks * 32 + 4 * kg;
      half4v aa = *(const half4v*)&sV[mrow][ka];
      half4v ab = *(const half4v*)&sV[mrow][ka + 16];
      half8v af = __builtin_shufflevector(aa, ab, 0, 1, 2, 3, 4, 5, 6, 7);
      half8v bf0 = *(const half8v*)&wm[(size_t)(2 * wid) * 2048 + ks * 512 + lane * 8];
      half8v bf1 = *(const half8v*)&wm[(size_t)(2 * wid + 1) * 2048 + ks * 512 + lane * 8];
      m0 = __builtin_amdgcn_mfma_f32_16x16x32_f16(af, bf0, m0, 0, 0, 0);
      m1 = __builtin_amdgcn_mfma_f32_16x16x32_f16(af, bf1, m1, 0, 0, 0);
    }
  }
  float bm0 = b_mlp[colw + mrow];
  float bm1 = b_mlp[colw + 16 + mrow];
#pragma unroll
  for (int r = 0; r < 4; ++r) {
    out[(size_t)(node0 + 4 * kg + r) * 128 + colw + mrow] = m0[r] + bm0;
    out[(size_t)(node0 + 4 * kg + r) * 128 + colw + 16 + mrow] = m1[r] + bm1;
  }
}

extern "C" void kernel_launch(void* const* d_in, const int* in_sizes, int n_in,
                              void* d_out, int out_size, void* d_ws, size_t ws_size,
                              hipStream_t stream) {
  const float* x      = (const float*)d_in[0];
  const int* ei       = (const int*)d_in[1];
  const float* W_low  = (const float*)d_in[2];
  const float* b_low  = (const float*)d_in[3];
  const float* W_band = (const float*)d_in[4];
  const float* b_band = (const float*)d_in[5];
  const float* apre_l = (const float*)d_in[6];
  const float* ach_l  = (const float*)d_in[7];
  const float* apre_b = (const float*)d_in[8];
  const float* ach_b  = (const float*)d_in[9];
  const float* W_mlp  = (const float*)d_in[10];
  const float* b_mlp  = (const float*)d_in[11];
  float* out = (float*)d_out;

  char* ws = (char*)d_ws;
  size_t off = 0;
  auto take = [&](size_t bytes) -> void* {
    void* p = ws + off;
    off = (off + bytes + 255) & ~(size_t)255;
    return p;
  };
  int*   deg    = (int*)take((size_t)NN * 4);
  int*   fill   = (int*)take((size_t)NN * 4);
  size_t zero_bytes = off;  // deg + fill region
  float* dinv   = (float*)take((size_t)NN * 4);
  int*   rowptr = (int*)take((size_t)(NN + 1) * 4);
  int*   col    = (int*)take((size_t)NE * 4);
  float* wgt    = (float*)take((size_t)NE * 4);
  _Float16* xh  = (_Float16*)take((size_t)NN * 128 * 2);
  _Float16* a1h = (_Float16*)take((size_t)NN * 128 * 2);
  _Float16* a2h = (_Float16*)take((size_t)NN * 128 * 2);
  _Float16* a3h = (_Float16*)take((size_t)NN * 128 * 2);
  _Float16* a4h = (_Float16*)take((size_t)NN * 128 * 2);
  _Float16* WTs = (_Float16*)take((size_t)9 * 16384 * 2);
  (void)ws_size; (void)in_sizes; (void)n_in; (void)out_size;

  hipMemsetAsync(d_ws, 0, zero_bytes, stream);
  k_prep<<<9, 256, 0, stream>>>(W_low, W_band, W_mlp, WTs);
  k_x2h<<<(NN * 32 + 255) / 256, 256, 0, stream>>>(x, xh);
  k_deg<<<(NE + 255) / 256, 256, 0, stream>>>(ei, deg);
  k_dinv<<<(NN + 255) / 256, 256, 0, stream>>>(deg, dinv);
  k_scan<<<1, 1024, 0, stream>>>(deg, rowptr);
  k_fill<<<(NE + 255) / 256, 256, 0, stream>>>(ei, dinv, rowptr, fill, col, wgt);
  k_hop16<<<(NN * 16 + 255) / 256, 256, 0, stream>>>(xh,  a1h, rowptr, col, wgt);
  k_hop16<<<(NN * 16 + 255) / 256, 256, 0, stream>>>(a1h, a2h, rowptr, col, wgt);
  k_hop16<<<(NN * 16 + 255) / 256, 256, 0, stream>>>(a2h, a3h, rowptr, col, wgt);
  k_hop16<<<(NN * 16 + 255) / 256, 256, 0, stream>>>(a3h, a4h, rowptr, col, wgt);
  k_fused<<<NN / TM, 256, 0, stream>>>(xh, a1h, a2h, a4h, WTs, b_low, b_band,
                                       apre_l, ach_l, apre_b, ach_b, b_mlp, out);
}